// Round 15
// baseline (2475614.648 us; speedup 1.0000x reference)
//
#include <hip/hip_runtime.h>
#include <hip/hip_fp16.h>
#include <math.h>

#define F 8
#define T_IN 336
#define T_OUT 96
#define D_OUT 2
#define NGRP 16
#define WPG 32
#define ROWS 16
#define NT 512
#define HROW 2048

#define WE0 0
#define WE1 1048576
#define WD0 3145728
#define WD1 4194304
#define W_TOTAL 6291456
#define HO0 0
#define HO1 262144
#define HBUF 131072

using f32x4 = __attribute__((ext_vector_type(4))) float;
using f16x8 = __attribute__((ext_vector_type(8))) _Float16;

struct Args {
  const float *src;
  const float *eWih0, *eb0, *eb1;
  const float *dWih0, *db0, *db1;
  const float *fcW, *fcb, *pW, *pb;
  const unsigned short *W;
  unsigned short *Hst;
  float *out;
  unsigned *cnt;
};

__device__ __forceinline__ float sigm(float x) { return 1.f / (1.f + __expf(-x)); }
__device__ __forceinline__ float tanh_f(float x) {
  float e = __expf(-2.f * fabsf(x));
  float r = (1.f - e) / (1.f + e);
  return copysignf(r, x);
}
__device__ __forceinline__ f32x4 mfma16(f16x8 a, f16x8 b, f32x4 c) {
  return __builtin_amdgcn_mfma_f32_16x16x32_f16(a, b, c, 0, 0, 0);
}
// XCD(L2)-scope data ops: group is XCD-confined, so sc0 (L1-bypass, L2-coherent) suffices
__device__ __forceinline__ void ld16_cg(uint4& d, const void* p) {
  asm volatile("global_load_dwordx4 %0, %1, off sc0" : "=v"(d) : "v"(p));
}
__device__ __forceinline__ void st2_cg(void* p, unsigned v) {
  asm volatile("global_store_short %0, %1, off sc0" :: "v"(p), "v"(v) : "memory");
}
__device__ __forceinline__ void st4_cg(void* p, unsigned v) {
  asm volatile("global_store_dword %0, %1, off sc0" :: "v"(p), "v"(v) : "memory");
}
__device__ __forceinline__ unsigned ld4_cg(const void* p) {
  unsigned v;
  asm volatile("global_load_dword %0, %1, off sc0\n\ts_waitcnt vmcnt(0)" : "=v"(v) : "v"(p) : "memory");
  return v;
}
__device__ __forceinline__ void vw0() { asm volatile("s_waitcnt vmcnt(0)" ::: "memory"); }
__device__ __forceinline__ void vw2() { asm volatile("s_waitcnt vmcnt(2)" ::: "memory"); }
__device__ __forceinline__ void vw4() { asm volatile("s_waitcnt vmcnt(4)" ::: "memory"); }

__global__ __launch_bounds__(256) void conv_kernel(
    const float* eWhh0, const float* eWih1, const float* eWhh1,
    const float* dWhh0, const float* dWih1, const float* dWhh1,
    unsigned short* W) {
  size_t i = (size_t)blockIdx.x * 256 + threadIdx.x;
  if (i >= W_TOTAL) return;
  int set, j;
  if (i < WE1)      { set = 0; j = (int)i; }
  else if (i < WD0) { set = 1; j = (int)(i - WE1); }
  else if (i < WD1) { set = 2; j = (int)(i - WD0); }
  else              { set = 3; j = (int)(i - WD1); }
  const int big = (set == 1 || set == 3);
  const int e = j & 7, lane = (j >> 3) & 63, r = j >> 9;
  const int kb = big ? (r & 31) : (r & 15);
  const int sw = big ? (r >> 5) : (r >> 4);
  const int s = sw >> 2, w = sw & 3;
  const int c = lane & 15;
  const int n = (c & 3) * 512 + 16 * s + 4 * w + (c >> 2);
  const int k = kb * 32 + (lane >> 4) * 8 + e;
  float v;
  if (set == 0)      v = eWhh0[(size_t)n * 512 + k];
  else if (set == 1) v = (k < 512) ? eWih1[(size_t)n * 512 + k] : eWhh1[(size_t)n * 512 + k - 512];
  else if (set == 2) v = dWhh0[(size_t)n * 512 + k];
  else               v = (k < 512) ? dWih1[(size_t)n * 512 + k] : dWhh1[(size_t)n * 512 + k - 512];
  W[i] = __half_as_ushort(__float2half_rn(v));
}

__global__ __launch_bounds__(NT, 2) void forecast_kernel(Args a) {
  extern __shared__ char smem[];
  char* HCa = smem;
  char* HCb = smem + 32768;
  float* TT = (float*)(smem + 65536);
  float* p_lds = TT + 8 * 288;
  float* x_lds = p_lds + 32;
  float* WxL = x_lds + 144;
  float* bL = WxL + 1152;
  float* pWb = bL + 256;

  const int tid = threadIdx.x;
  // XCD-confined groups: blockIdx%8 = XCD (round-robin dispatch), 32 slices/XCD
  const int xcd = blockIdx.x & 7;
  const int s = blockIdx.x >> 3;        // unit slice 0..31
  const int gA = xcd * 2, gB = xcd * 2 + 1;
  const int lane = tid & 63, wid = tid >> 6;
  const int bb = lane & 15;
  const int lq = lane >> 4;
  const int isL0 = (wid < 4);
  const int w4 = isL0 ? wid : wid - 4;
  const int uu = lane >> 4;
  const int unitL = w4 * 4 + uu;
  float* TTw = TT + wid * 288;
  unsigned* slotA = a.cnt + gA * 32;
  unsigned* slotB = a.cnt + gB * 32;
  unsigned bsA = 0, bsB = 0;

  unsigned short* H0 = a.Hst + HO0;
  unsigned short* H1 = a.Hst + HO1;

  const int nkbE = isL0 ? 16 : 32;
  const unsigned short* wE = a.W + (isL0 ? WE0 : WE1) + (size_t)(s * 4 + w4) * nkbE * 512 + lane * 8;
  const unsigned short* wD = a.W + (isL0 ? WD0 : WD1) + (size_t)(s * 4 + w4) * nkbE * 512 + lane * 8;

  f16x8 wreg[32];
  auto loadW = [&](const unsigned short* wp) {
    #pragma unroll
    for (int kb = 0; kb < 32; ++kb)
      if (kb < nkbE) wreg[kb] = *(const f16x8*)(wp + (size_t)kb * 512);
  };
  loadW(wE);

  for (int e = tid; e < 1152; e += NT) {
    int set = e / 576, e2 = e % 576, row = e2 / 9, k = e2 % 9;
    const float* sw = set ? a.dWih0 : a.eWih0;
    WxL[e] = (k < 8) ? sw[(size_t)((row >> 4) * 512 + 16 * s + (row & 15)) * 8 + k] : 0.f;
  }
  if (tid < 256) {
    int bs = tid >> 6, q = (tid >> 4) & 3, u2 = tid & 15;
    const float* sp = bs == 0 ? a.eb0 : bs == 1 ? a.eb1 : bs == 2 ? a.db0 : a.db1;
    bL[tid] = sp[q * 512 + 16 * s + u2];
  }
  if (tid < 16) pWb[tid] = a.pW[tid];
  else if (tid < 24) pWb[tid] = a.pb[tid - 16];
  else if (tid < 26) pWb[tid] = a.fcb[tid - 24];
  __syncthreads();

  float cA = 0.f, cB = 0.f;
  const int srow = tid >> 5, seg = tid & 31;
  const int wswz = (srow & 7) << 4;
  const int aswz = (bb & 7) << 4;

  uint4 pf0, pf1, pf2, pf3;   // prefetch registers

  auto pollG = [&](unsigned* slots, unsigned target) {
    if (wid == 0) {
      const unsigned* p = slots + (lane & 31);
      const bool self = (lane >= 32) || ((lane & 31) == s);
      long gd = 0;
      for (;;) {
        unsigned v = ld4_cg(p);
        if (__all((int)(self || v >= target))) break;
        __builtin_amdgcn_s_sleep(1);
        if (++gd > (1L << 15)) break;   // fail-fast
      }
    }
    __syncthreads();
    asm volatile("" ::: "memory");
  };
  auto pub = [&](unsigned* slots, unsigned target) {
    if (tid == 0) st4_cg((void*)(slots + s), target);
  };
  auto issue2 = [&](const unsigned short* b0, const unsigned short* b1, int g) {
    const unsigned short* p0 = b0 + (size_t)(16 * g + srow) * 512 + seg * 8;
    const unsigned short* p1 = b1 + (size_t)(16 * g + srow) * 512 + seg * 8;
    ld16_cg(pf0, p0); ld16_cg(pf1, p0 + 256); ld16_cg(pf2, p1); ld16_cg(pf3, p1 + 256);
  };
  auto issue1 = [&](const unsigned short* b0, int g) {
    const unsigned short* p0 = b0 + (size_t)(16 * g + srow) * 512 + seg * 8;
    ld16_cg(pf0, p0); ld16_cg(pf1, p0 + 256);
  };
  auto write2 = [&](char* HC) {
    vw0();
    __builtin_amdgcn_sched_barrier(0);
    char* d = HC + srow * HROW + ((seg * 16) ^ wswz);
    *(uint4*)d = pf0; *(uint4*)(d + 512) = pf1;
    *(uint4*)(d + 1024) = pf2; *(uint4*)(d + 1536) = pf3;
    __syncthreads();
  };
  auto write1 = [&](char* HC, int plane) {
    vw0();
    __builtin_amdgcn_sched_barrier(0);
    char* d = HC + srow * HROW + plane + ((seg * 16) ^ wswz);
    *(uint4*)d = pf0; *(uint4*)(d + 512) = pf1;
    __syncthreads();
  };

  auto encCompute = [&](char* HC, float& c01, int g, int t) {
    const int nbuf = (t & 1) ^ 1;
    const bool active = isL0 ? (t < T_IN) : (t >= 1);
    if (active) {
      f32x4 acc = {0.f, 0.f, 0.f, 0.f};
      const char* arow = HC + bb * HROW;
      #pragma unroll
      for (int kb = 0; kb < 32; ++kb)
        if (kb < nkbE)
          acc = mfma16(*(const f16x8*)(arow + ((lq * 16 + kb * 64) ^ aswz)), wreg[kb], acc);
      #pragma unroll
      for (int j = 0; j < 4; ++j) TTw[bb * 18 + lq * 4 + j] = acc[j];
      float ac[4];
      #pragma unroll
      for (int q = 0; q < 4; ++q)
        ac[q] = TTw[(4 * uu + q) * 18 + bb] + bL[(isL0 ? 0 : 64) + q * 16 + unitL];
      const int rowG = 16 * g + bb;
      if (isL0) {
        const float* xr = a.src + (size_t)rowG * (T_IN * F) + t * F;
        float4 x0 = *(const float4*)xr, x1 = *(const float4*)(xr + 4);
        float xv[8] = {x0.x, x0.y, x0.z, x0.w, x1.x, x1.y, x1.z, x1.w};
        #pragma unroll
        for (int q = 0; q < 4; ++q)
          #pragma unroll
          for (int k = 0; k < 8; ++k)
            ac[q] = fmaf(xv[k], WxL[(q * 16 + unitL) * 9 + k], ac[q]);
      }
      c01 = sigm(ac[1]) * c01 + sigm(ac[0]) * tanh_f(ac[2]);
      float h = sigm(ac[3]) * tanh_f(c01);
      unsigned short* hplane = (isL0 ? H0 : H1) + (size_t)nbuf * HBUF;
      st2_cg((void*)(hplane + (size_t)rowG * 512 + 16 * s + unitL),
             (unsigned)__half_as_ushort(__float2half_rn(h)));
    }
  };

  auto fcw = [&](char* HC, int g, int t) {
    const int pb_ = lane & 15, dd = (lane >> 4) & 1, hf = lane >> 5;
    const char* hp = HC + pb_ * HROW;
    const int fswz = (pb_ & 7) << 4;
    const float* wr = a.fcW + dd * 512 + hf * 256;
    float r = 0.f;
    #pragma unroll 8
    for (int j = 0; j < 32; ++j) {
      f16x8 v = *(const f16x8*)(hp + ((1024 + hf * 512 + j * 16) ^ fswz));
      float4 w0 = *(const float4*)(wr + j * 8);
      float4 w1 = *(const float4*)(wr + j * 8 + 4);
      r = fmaf((float)v[0], w0.x, r); r = fmaf((float)v[1], w0.y, r);
      r = fmaf((float)v[2], w0.z, r); r = fmaf((float)v[3], w0.w, r);
      r = fmaf((float)v[4], w1.x, r); r = fmaf((float)v[5], w1.y, r);
      r = fmaf((float)v[6], w1.z, r); r = fmaf((float)v[7], w1.w, r);
    }
    r += __shfl_xor(r, 32);
    if (lane < 32) {
      float pred = r + pWb[24 + dd];
      if (t == 0) pred = a.src[(size_t)(16 * g + pb_) * (T_IN * F) + 335 * F + dd * 2];
      p_lds[pb_ * 2 + dd] = pred;
      if (s == 0 && t > 0)
        a.out[(size_t)(16 * g + pb_) * (T_OUT * D_OUT) + (size_t)(t - 1) * D_OUT + dd] = pred;
    }
    const int bx = lane >> 2, j0 = (lane & 3) * 2;
    float pr0 = p_lds[bx * 2], pr1 = p_lds[bx * 2 + 1];
    x_lds[bx * 9 + j0]     = pWb[16 + j0]     + pr0 * pWb[j0 * 2]       + pr1 * pWb[j0 * 2 + 1];
    x_lds[bx * 9 + j0 + 1] = pWb[16 + j0 + 1] + pr0 * pWb[(j0 + 1) * 2] + pr1 * pWb[(j0 + 1) * 2 + 1];
  };

  auto decCompute1 = [&](char* HC, float& c01, int g, int t) {
    const int pA = t & 1;
    if (isL0) {
      f32x4 acc = {0.f, 0.f, 0.f, 0.f};
      const char* arow = HC + bb * HROW;
      #pragma unroll
      for (int kb = 0; kb < 16; ++kb)
        acc = mfma16(*(const f16x8*)(arow + ((lq * 16 + kb * 64) ^ aswz)), wreg[kb], acc);
      #pragma unroll
      for (int j = 0; j < 4; ++j) TTw[bb * 18 + lq * 4 + j] = acc[j];
    } else if (wid == 4) {
      fcw(HC, g, t);
    }
    __syncthreads();
    if (isL0) {
      float ac[4];
      #pragma unroll
      for (int q = 0; q < 4; ++q)
        ac[q] = TTw[(4 * uu + q) * 18 + bb] + bL[128 + q * 16 + unitL];
      #pragma unroll
      for (int q = 0; q < 4; ++q)
        #pragma unroll
        for (int k = 0; k < 8; ++k)
          ac[q] = fmaf(x_lds[bb * 9 + k], WxL[576 + (q * 16 + unitL) * 9 + k], ac[q]);
      c01 = sigm(ac[1]) * c01 + sigm(ac[0]) * tanh_f(ac[2]);
      float h = sigm(ac[3]) * tanh_f(c01);
      unsigned short* hplane = H0 + (size_t)(pA ^ 1) * HBUF;
      st2_cg((void*)(hplane + (size_t)(16 * g + bb) * 512 + 16 * s + unitL),
             (unsigned)__half_as_ushort(__float2half_rn(h)));
    }
  };

  auto decCompute2 = [&](char* HC, float& c01, int g, int t) {
    const int pA = t & 1;
    if (!isL0) {
      f32x4 acc = {0.f, 0.f, 0.f, 0.f};
      const char* arow = HC + bb * HROW;
      #pragma unroll
      for (int kb = 0; kb < 32; ++kb)
        acc = mfma16(*(const f16x8*)(arow + ((lq * 16 + kb * 64) ^ aswz)), wreg[kb], acc);
      #pragma unroll
      for (int j = 0; j < 4; ++j) TTw[bb * 18 + lq * 4 + j] = acc[j];
      float ac[4];
      #pragma unroll
      for (int q = 0; q < 4; ++q)
        ac[q] = TTw[(4 * uu + q) * 18 + bb] + bL[192 + q * 16 + unitL];
      c01 = sigm(ac[1]) * c01 + sigm(ac[0]) * tanh_f(ac[2]);
      float h = sigm(ac[3]) * tanh_f(c01);
      unsigned short* hplane = H1 + (size_t)pA * HBUF;
      st2_cg((void*)(hplane + (size_t)(16 * g + bb) * 512 + 16 * s + unitL),
             (unsigned)__half_as_ushort(__float2half_rn(h)));
    }
  };

  auto epiCompute = [&](char* HC, int g) {
    if (wid == 4 && s == 0) {
      const int pb_ = lane & 15, dd = (lane >> 4) & 1, hf = lane >> 5;
      const char* hp = HC + pb_ * HROW;
      const int fswz = (pb_ & 7) << 4;
      const float* wr = a.fcW + dd * 512 + hf * 256;
      float r = 0.f;
      #pragma unroll 8
      for (int j = 0; j < 32; ++j) {
        f16x8 v = *(const f16x8*)(hp + ((1024 + hf * 512 + j * 16) ^ fswz));
        float4 w0 = *(const float4*)(wr + j * 8);
        float4 w1 = *(const float4*)(wr + j * 8 + 4);
        r = fmaf((float)v[0], w0.x, r); r = fmaf((float)v[1], w0.y, r);
        r = fmaf((float)v[2], w0.z, r); r = fmaf((float)v[3], w0.w, r);
        r = fmaf((float)v[4], w1.x, r); r = fmaf((float)v[5], w1.y, r);
        r = fmaf((float)v[6], w1.z, r); r = fmaf((float)v[7], w1.w, r);
      }
      r += __shfl_xor(r, 32);
      if (lane < 32)
        a.out[(size_t)(16 * g + pb_) * (T_OUT * D_OUT) + (size_t)95 * D_OUT + dd] = r + pWb[24 + dd];
    }
  };

  // ================= prologue =================
  pollG(slotA, bsA);
  issue2(H0 + 0 * HBUF, H1 + 0 * HBUF, gA);

  // ================= encoder (pipelined dual-group) =================
  for (int t = 0; t <= T_IN; ++t) {
    const size_t bo = (size_t)(t & 1) * HBUF;
    // --- EA(t) ---
    write2(HCa);
    encCompute(HCa, cA, gA, t);
    pollG(slotB, bsB);
    issue2(H0 + bo, H1 + bo, gB);
    vw4(); __syncthreads(); pub(slotA, ++bsA);
    // --- EB(t) ---
    write2(HCb);
    encCompute(HCb, cB, gB, t);
    pollG(slotA, bsA);
    if (t < T_IN) {
      const size_t bn = (size_t)((t + 1) & 1) * HBUF;
      issue2(H0 + bn, H1 + bn, gA);
      vw4();
    } else {
      issue1(H1 + 1 * HBUF, gA);
      vw2();
    }
    __syncthreads(); pub(slotB, ++bsB);
  }

  loadW(wD);

  // ================= decoder (4-phase pipelined) =================
  for (int t = 0; t < T_OUT; ++t) {
    const int pA = t & 1;
    // --- DA1(t) ---
    write1(HCa, 1024);
    decCompute1(HCa, cA, gA, t);
    pollG(slotB, bsB);
    issue1(H1 + (size_t)(pA ^ 1) * HBUF, gB);
    vw2(); __syncthreads(); pub(slotA, ++bsA);
    // --- DB1(t) ---
    write1(HCb, 1024);
    decCompute1(HCb, cB, gB, t);
    pollG(slotA, bsA);
    issue1(H0 + (size_t)(pA ^ 1) * HBUF, gA);
    vw2(); __syncthreads(); pub(slotB, ++bsB);
    // --- DA2(t) ---
    write1(HCa, 0);
    decCompute2(HCa, cA, gA, t);
    pollG(slotB, bsB);
    issue1(H0 + (size_t)(pA ^ 1) * HBUF, gB);
    vw2(); __syncthreads(); pub(slotA, ++bsA);
    // --- DB2(t) ---
    write1(HCb, 0);
    decCompute2(HCb, cB, gB, t);
    pollG(slotA, bsA);
    issue1(H1 + (size_t)(((t + 1) & 1) ^ 1) * HBUF, gA);
    vw2(); __syncthreads(); pub(slotB, ++bsB);
  }

  // ================= epilogue =================
  write1(HCa, 1024);
  epiCompute(HCa, gA);
  pollG(slotB, bsB);
  issue1(H1 + 1 * HBUF, gB);
  write1(HCb, 1024);
  epiCompute(HCb, gB);
}

extern "C" void kernel_launch(void* const* d_in, const int* in_sizes, int n_in,
                              void* d_out, int out_size, void* d_ws, size_t ws_size,
                              hipStream_t stream) {
  (void)in_sizes; (void)n_in; (void)out_size; (void)ws_size;
  const float* src   = (const float*)d_in[0];
  const float* eWih0 = (const float*)d_in[1];
  const float* eWhh0 = (const float*)d_in[2];
  const float* eb0   = (const float*)d_in[3];
  const float* eWih1 = (const float*)d_in[4];
  const float* eWhh1 = (const float*)d_in[5];
  const float* eb1   = (const float*)d_in[6];
  const float* dWih0 = (const float*)d_in[7];
  const float* dWhh0 = (const float*)d_in[8];
  const float* db0   = (const float*)d_in[9];
  const float* dWih1 = (const float*)d_in[10];
  const float* dWhh1 = (const float*)d_in[11];
  const float* db1   = (const float*)d_in[12];
  const float* fcW   = (const float*)d_in[13];
  const float* fcb   = (const float*)d_in[14];
  const float* pW    = (const float*)d_in[15];
  const float* pb    = (const float*)d_in[16];

  unsigned char* ws = (unsigned char*)d_ws;
  unsigned* cnt = (unsigned*)ws;                       // 4 KB slot barriers
  unsigned short* W = (unsigned short*)(ws + 4096);    // 12.6 MB fp16 tiled weights
  unsigned short* Hst = W + W_TOTAL;                   // 1 MB fp16 h-state

  (void)hipMemsetAsync(d_ws, 0, 4096, stream);
  (void)hipMemsetAsync((void*)Hst, 0, (size_t)4 * HBUF * sizeof(unsigned short), stream);

  hipLaunchKernelGGL(conv_kernel, dim3(W_TOTAL / 256), dim3(256), 0, stream,
                     eWhh0, eWih1, eWhh1, dWhh0, dWih1, dWhh1, W);

  Args a;
  a.src = src; a.eWih0 = eWih0; a.eb0 = eb0; a.eb1 = eb1;
  a.dWih0 = dWih0; a.db0 = db0; a.db1 = db1;
  a.fcW = fcW; a.fcb = fcb; a.pW = pW; a.pb = pb;
  a.W = W; a.Hst = Hst; a.out = (float*)d_out; a.cnt = cnt;

  const size_t smem_bytes = 65536 + (2304 + 32 + 144 + 1152 + 256 + 32) * sizeof(float);
  hipLaunchKernelGGL(forecast_kernel, dim3(NGRP / 2 * WPG), dim3(NT), smem_bytes, stream, a);
}